// Round 1
// baseline (504.924 us; speedup 1.0000x reference)
//
#include <hip/hip_runtime.h>
#include <stdint.h>

// Problem constants (B=4, L=1024, C=768, H=12, DK=64, MAXREL=7)
// Outputs: z [4,1024,768] fp32 then scores [4,12,1024,1024] fp32, concatenated.

typedef __attribute__((ext_vector_type(4))) float f32x4;
typedef __attribute__((ext_vector_type(4))) int   i32x4;
typedef __attribute__((ext_vector_type(8))) short short8;   // 8 bf16 (4 VGPRs) - MFMA A/B frag
typedef __attribute__((ext_vector_type(4))) unsigned int u32x4;
typedef __attribute__((ext_vector_type(2))) unsigned int u32x2;

__device__ __forceinline__ unsigned short f2bf(float f) {   // fp32 -> bf16, RNE
  unsigned int u = __float_as_uint(f);
  u += 0x7fffu + ((u >> 16) & 1u);
  return (unsigned short)(u >> 16);
}

// ---------------------------------------------------------------------------
// Kernel 1: qx,kx,vx fp32 -> bf16
__global__ __launch_bounds__(256) void conv_x_kernel(
    const float* __restrict__ qx, const float* __restrict__ kx,
    const float* __restrict__ vx, unsigned short* __restrict__ out) {
  int v = blockIdx.x * 256 + threadIdx.x;       // float4 index
  int mat = v / 786432;
  int r = v - mat * 786432;
  const float* src = (mat == 0) ? qx : (mat == 1) ? kx : vx;
  f32x4 x = ((const f32x4*)src)[r];
  union { unsigned short s[4]; u32x2 u; } o;
  o.s[0] = f2bf(x[0]); o.s[1] = f2bf(x[1]); o.s[2] = f2bf(x[2]); o.s[3] = f2bf(x[3]);
  ((u32x2*)out)[v] = o.u;
}

// ---------------------------------------------------------------------------
// Kernel 2: W [768k][768n] fp32 -> WT [768n][768k] bf16, for WQ,WK,WV,WO.
__global__ __launch_bounds__(256) void conv_w_kernel(
    const float* __restrict__ w0, const float* __restrict__ w1,
    const float* __restrict__ w2, const float* __restrict__ w3,
    unsigned short* __restrict__ out) {
  __shared__ float T[64][65];
  int bx = blockIdx.x;
  int mat = bx / 144; int t2 = bx - mat * 144;
  int kt = t2 / 12, nt = t2 - kt * 12;
  int k0 = kt * 64, n0 = nt * 64;
  const float* W = (mat == 0) ? w0 : (mat == 1) ? w1 : (mat == 2) ? w2 : w3;
  unsigned short* WT = out + (size_t)mat * 589824;
  int t = threadIdx.x;
  int lr = t >> 4;
  int lc = (t & 15) * 4;
#pragma unroll
  for (int p = 0; p < 4; p++) {
    int row = p * 16 + lr;
    f32x4 x = *(const f32x4*)&W[(size_t)(k0 + row) * 768 + n0 + lc];
    T[lc + 0][row] = x[0]; T[lc + 1][row] = x[1];
    T[lc + 2][row] = x[2]; T[lc + 3][row] = x[3];
  }
  __syncthreads();
#pragma unroll
  for (int p = 0; p < 4; p++) {
    int row = p * 16 + lr;
    union { unsigned short s[4]; u32x2 u; } o;
    o.s[0] = f2bf(T[row][lc + 0]); o.s[1] = f2bf(T[row][lc + 1]);
    o.s[2] = f2bf(T[row][lc + 2]); o.s[3] = f2bf(T[row][lc + 3]);
    *(u32x2*)&WT[(size_t)(n0 + row) * 768 + k0 + lc] = o.u;
  }
}

// ---------------------------------------------------------------------------
// Kernel 3: QKV projection GEMM, software-pipelined (1 barrier/iter, reg prefetch).
// mat 0 -> q [B,H,L,64]; mat 1 -> k [B,H,L,64]; mat 2 -> vT [B,H,64,L] via LDS
// transpose bounce (coalesced dwordx4 stores; the R1 scatter was ~16x L2 write amp).
__global__ __launch_bounds__(256, 2) void qkv_gemm_kernel(
    const unsigned short* __restrict__ xbf, const unsigned short* __restrict__ wt,
    const float* __restrict__ bq, const float* __restrict__ bk, const float* __restrict__ bv,
    unsigned short* __restrict__ qo, unsigned short* __restrict__ ko,
    unsigned short* __restrict__ vto) {
  __shared__ unsigned short SM[2][2][128 * 72];   // [buf][A/B]
  int bx = blockIdx.x;
  int mat = bx / 192; int rem = bx - mat * 192;
  int mt = rem / 6, nt = rem - mt * 6;
  int m0 = mt * 128, n0 = nt * 128;
  const unsigned short* A = xbf + (size_t)mat * 4096 * 768;
  const unsigned short* Bm = wt + (size_t)mat * 768 * 768;
  int t = threadIdx.x;
  int wave = t >> 6, lane = t & 63;
  int wm = (wave >> 1) * 64, wn = (wave & 1) * 64;
  int col = lane & 15, quad = lane >> 4;
  int srow = t >> 3;
  int sch = (t & 7) * 8;

  f32x4 acc[4][4];
#pragma unroll
  for (int i = 0; i < 4; i++)
#pragma unroll
    for (int j = 0; j < 4; j++) acc[i][j] = (f32x4){0.f, 0.f, 0.f, 0.f};

  u32x4 ra[4], rb[4];
  // prologue: tile 0 -> LDS0; tile 1 -> regs
#pragma unroll
  for (int p = 0; p < 4; p++) {
    ra[p] = *(const u32x4*)&A[(size_t)(m0 + srow + p * 32) * 768 + sch];
    rb[p] = *(const u32x4*)&Bm[(size_t)(n0 + srow + p * 32) * 768 + sch];
  }
#pragma unroll
  for (int p = 0; p < 4; p++) {
    *(u32x4*)&SM[0][0][(srow + p * 32) * 72 + sch] = ra[p];
    *(u32x4*)&SM[0][1][(srow + p * 32) * 72 + sch] = rb[p];
  }
#pragma unroll
  for (int p = 0; p < 4; p++) {
    ra[p] = *(const u32x4*)&A[(size_t)(m0 + srow + p * 32) * 768 + 64 + sch];
    rb[p] = *(const u32x4*)&Bm[(size_t)(n0 + srow + p * 32) * 768 + 64 + sch];
  }
  __syncthreads();

  for (int it = 0; it < 12; ++it) {
    const unsigned short* As = SM[it & 1][0];
    const unsigned short* Bs = SM[it & 1][1];
#pragma unroll
    for (int c = 0; c < 2; c++) {
      short8 af[4], bf[4];
#pragma unroll
      for (int i = 0; i < 4; i++) {
        af[i] = *(const short8*)&As[(wm + i * 16 + col) * 72 + c * 32 + quad * 8];
        bf[i] = *(const short8*)&Bs[(wn + i * 16 + col) * 72 + c * 32 + quad * 8];
      }
#pragma unroll
      for (int i = 0; i < 4; i++)
#pragma unroll
        for (int j = 0; j < 4; j++)
          acc[i][j] = __builtin_amdgcn_mfma_f32_16x16x32_bf16(af[i], bf[j], acc[i][j], 0, 0, 0);
    }
    if (it < 11) {
      unsigned short* An = SM[(it + 1) & 1][0];
      unsigned short* Bn = SM[(it + 1) & 1][1];
#pragma unroll
      for (int p = 0; p < 4; p++) {
        *(u32x4*)&An[(srow + p * 32) * 72 + sch] = ra[p];
        *(u32x4*)&Bn[(srow + p * 32) * 72 + sch] = rb[p];
      }
      if (it < 10) {
        int kk2 = (it + 2) * 64;
#pragma unroll
        for (int p = 0; p < 4; p++) {
          ra[p] = *(const u32x4*)&A[(size_t)(m0 + srow + p * 32) * 768 + kk2 + sch];
          rb[p] = *(const u32x4*)&Bm[(size_t)(n0 + srow + p * 32) * 768 + kk2 + sch];
        }
      }
      __syncthreads();
    }
  }

  if (mat != 2) {
    const float* bias = (mat == 0) ? bq : bk;
    unsigned short* dst = (mat == 0) ? qo : ko;
#pragma unroll
    for (int j = 0; j < 4; j++) {
      int gn = n0 + wn + j * 16 + col;
      float bsv = bias[gn];
      int h = gn >> 6, d = gn & 63;
#pragma unroll
      for (int i = 0; i < 4; i++) {
#pragma unroll
        for (int r = 0; r < 4; r++) {
          int gm = m0 + wm + i * 16 + quad * 4 + r;
          int b = gm >> 10, l = gm & 1023;
          dst[((size_t)(b * 12 + h) * 1024 + l) * 64 + d] = f2bf(acc[i][j][r] + bsv);
        }
      }
    }
  } else {
    // transpose bounce: Tr[n_local][m_local], stride 132 shorts (33792 B <= 36864 SM)
    unsigned short* Tr = &SM[0][0][0];
    __syncthreads();   // all waves done with SM reads (last iter used SM[1]; Tr spans SM[0])
#pragma unroll
    for (int j = 0; j < 4; j++) {
      int n = wn + j * 16 + col;
      float bsv = bv[n0 + n];
#pragma unroll
      for (int i = 0; i < 4; i++) {
        int m = wm + i * 16 + quad * 4;
        union { unsigned short s[4]; u32x2 u; } pk;
#pragma unroll
        for (int r = 0; r < 4; r++) pk.s[r] = f2bf(acc[i][j][r] + bsv);
        *(u32x2*)&Tr[(size_t)n * 132 + m] = pk.u;
      }
    }
    __syncthreads();
#pragma unroll
    for (int p = 0; p < 8; p++) {
      int row = (t >> 4) + p * 16;          // n_local 0..127
      int ch = (t & 15) * 8;                // m_local chunk
      u32x4 val = *(const u32x4*)&Tr[(size_t)row * 132 + ch];
      int gn = n0 + row;
      int h = gn >> 6, d = gn & 63;
      int gm = m0 + ch;
      int b = gm >> 10, l = gm & 1023;
      *(u32x4*)&vto[((size_t)(b * 12 + h) * 64 + d) * 1024 + l] = val;
    }
  }
}

// ---------------------------------------------------------------------------
// Kernel 4: fused attention, software-pipelined.
// One barrier/iter: double-buffered K/V LDS; K/V prefetched 2 iters ahead in
// regs; preS AND mask prefetched 1 iter ahead in regs.
// R2 changes vs R1:
//  - j-tile phase stagger: block's start tile jt0 = i-tile index. All 768
//    blocks were sweeping the same 256B column band of 4KB-strided rows in
//    lockstep -> DRAM channel/bank conflicts (2.9 TB/s at floor bytes).
//    Online softmax is j-order-agnostic, so visiting tiles (jt0+n)&15 spreads
//    concurrent traffic over all 16 column phases. Same-(b,it) blocks across h
//    stay co-phased, preserving mask L3 reuse.
//  - mask prefetched 1 tile ahead (was same-iter: L3-latency load gated the
//    epilogue).
//  - preS loads / scores stores nontemporal: single-use 400MB streams, keep
//    them from thrashing L2 (mask/K/V working set stays resident).
struct KV { u32x4 k0, k1, v0, v1; };

__device__ __forceinline__ void attn_body(
    int j0, int j1, int j2, bool pf1, bool pf2,
    const unsigned short* KsC, const unsigned short* VsC,
    unsigned short* KsN, unsigned short* VsN,
    f32x4* preC, f32x4* preN, i32x4* mkC, i32x4* mkN, KV& kvW, KV& kvF,
    const short8* qf, f32x4* oacc, float& m_s, float& l_s,
    const unsigned short* kbase, const unsigned short* vbase,
    const float* pbase, const int* mbase, float* sbase,
    unsigned short* Ps, const float* eK, const float* eB,
    int lrow, int gi, int srow, int sch, int col, int quad, int wave) {
  // issue preS + mask loads (tile j1)
  if (pf1) {
#pragma unroll
    for (int ns = 0; ns < 4; ns++) {
      preN[ns] = __builtin_nontemporal_load(
          (const f32x4*)&pbase[(size_t)lrow * 1024 + j1 + ns * 16 + quad * 4]);
      mkN[ns] = *(const i32x4*)&mbase[(size_t)lrow * 1024 + j1 + ns * 16 + quad * 4];
    }
  }
  // issue K/V loads (tile j2)
  if (pf2) {
    kvF.k0 = *(const u32x4*)&kbase[(size_t)(j2 + srow) * 64 + sch];
    kvF.k1 = *(const u32x4*)&kbase[(size_t)(j2 + srow + 32) * 64 + sch];
    kvF.v0 = *(const u32x4*)&vbase[(size_t)srow * 1024 + j2 + sch];
    kvF.v1 = *(const u32x4*)&vbase[(size_t)(srow + 32) * 1024 + j2 + sch];
  }
  // S^T tile: rows j (quad*4+reg), cols i (lane&15)
  f32x4 sacc[4];
#pragma unroll
  for (int ns = 0; ns < 4; ns++) sacc[ns] = (f32x4){0.f, 0.f, 0.f, 0.f};
#pragma unroll
  for (int c = 0; c < 2; c++) {
#pragma unroll
    for (int ns = 0; ns < 4; ns++) {
      short8 kf = *(const short8*)&KsC[(ns * 16 + col) * 72 + c * 32 + quad * 8];
      sacc[ns] = __builtin_amdgcn_mfma_f32_16x16x32_bf16(kf, qf[c], sacc[ns], 0, 0, 0);
    }
  }
  // epilogue: scale, rel-pos, preScores, mask, write scores
  float sv[4][4];
#pragma unroll
  for (int ns = 0; ns < 4; ns++) {
    int gj0 = j0 + ns * 16 + quad * 4;
    f32x4 sout;
#pragma unroll
    for (int r = 0; r < 4; r++) {
      int dd = gi - (gj0 + r); dd = dd < 0 ? -dd : dd;
      int idx;
      if (dd <= 7) idx = dd;
      else { idx = 38 - __clz(dd - 7); idx = idx > 14 ? 14 : idx; }  // exact floor(7+log2)
      float s = sacc[ns][r] * 0.125f * eK[idx] + eB[idx] + preC[ns][r];
      if (mkC[ns][r] == 0) s = -32768.0f;
      sout[r] = s; sv[ns][r] = s;
    }
    __builtin_nontemporal_store(sout, (f32x4*)&sbase[(size_t)lrow * 1024 + gj0]);
  }
  // online softmax
  float mx = sv[0][0];
#pragma unroll
  for (int ns = 0; ns < 4; ns++)
#pragma unroll
    for (int r = 0; r < 4; r++) mx = fmaxf(mx, sv[ns][r]);
  mx = fmaxf(mx, __shfl_xor(mx, 16));
  mx = fmaxf(mx, __shfl_xor(mx, 32));
  float mn = fmaxf(m_s, mx);
  float alpha = __expf(m_s - mn);
  float rs = 0.f;
#pragma unroll
  for (int ns = 0; ns < 4; ns++)
#pragma unroll
    for (int r = 0; r < 4; r++) { float p = __expf(sv[ns][r] - mn); sv[ns][r] = p; rs += p; }
  rs += __shfl_xor(rs, 16); rs += __shfl_xor(rs, 32);
  l_s = l_s * alpha + rs;
  m_s = mn;
#pragma unroll
  for (int nd = 0; nd < 4; nd++)
#pragma unroll
    for (int r = 0; r < 4; r++) oacc[nd][r] *= alpha;
  // P tile -> LDS (wave-private rows; same-wave RAW, compiler inserts lgkmcnt)
#pragma unroll
  for (int ns = 0; ns < 4; ns++) {
    union { unsigned short s[4]; u32x2 u; } pk;
#pragma unroll
    for (int r = 0; r < 4; r++) pk.s[r] = f2bf(sv[ns][r]);
    *(u32x2*)&Ps[(size_t)lrow * 72 + ns * 16 + quad * 4] = pk.u;
  }
  // Z^T += V^T * P^T
#pragma unroll
  for (int c2 = 0; c2 < 2; c2++) {
    short8 pf = *(const short8*)&Ps[(wave * 16 + col) * 72 + c2 * 32 + quad * 8];
#pragma unroll
    for (int nd = 0; nd < 4; nd++) {
      short8 vf = *(const short8*)&VsC[(nd * 16 + col) * 72 + c2 * 32 + quad * 8];
      oacc[nd] = __builtin_amdgcn_mfma_f32_16x16x32_bf16(vf, pf, oacc[nd], 0, 0, 0);
    }
  }
  // stage next tile -> alternate buffers; single barrier per iteration
  if (pf1) {
    *(u32x4*)&KsN[srow * 72 + sch] = kvW.k0;
    *(u32x4*)&KsN[(srow + 32) * 72 + sch] = kvW.k1;
    *(u32x4*)&VsN[srow * 72 + sch] = kvW.v0;
    *(u32x4*)&VsN[(srow + 32) * 72 + sch] = kvW.v1;
    __syncthreads();
  }
}

__global__ __launch_bounds__(256, 3) void attn_kernel(
    const unsigned short* __restrict__ q, const unsigned short* __restrict__ k,
    const unsigned short* __restrict__ vt, const float* __restrict__ preS,
    const int* __restrict__ maskP, const float* __restrict__ embK,
    const float* __restrict__ embB, float* __restrict__ scores,
    unsigned short* __restrict__ zpre) {
  __shared__ unsigned short Qs[64 * 72];        // aliased as Ps after qf read (wave-private rows)
  __shared__ unsigned short KsB[2][64 * 72];
  __shared__ unsigned short VsB[2][64 * 72];
  __shared__ float eKs[16], eBs[16];
  int bx = blockIdx.x;
  int slice = bx % 48, it = bx / 48;
  int b = slice / 12, h = slice - b * 12;
  int i0 = it * 64;
  int t = threadIdx.x, wave = t >> 6, lane = t & 63;
  int col = lane & 15, quad = lane >> 4;
  int srow = t >> 3, sch = (t & 7) * 8;

  if (t < 15) { eKs[t] = embK[t * 12 + h]; eBs[t] = embB[t * 12 + h]; }

  const unsigned short* qbase = q + ((size_t)(b * 12 + h) * 1024 + i0) * 64;
  const unsigned short* kbase = k + (size_t)(b * 12 + h) * 1024 * 64;
  const unsigned short* vbase = vt + (size_t)(b * 12 + h) * 64 * 1024;
  const float* pbase = preS + ((size_t)(b * 12 + h) * 1024 + i0) * 1024;
  const int* mbase = maskP + ((size_t)b * 1024 + i0) * 1024;
  float* sbase = scores + ((size_t)(b * 12 + h) * 1024 + i0) * 1024;
  int lrow = wave * 16 + col;
  int gi = i0 + lrow;

#pragma unroll
  for (int p = 0; p < 2; p++) {
    int row = srow + p * 32;
    *(u32x4*)&Qs[row * 72 + sch] = *(const u32x4*)&qbase[(size_t)row * 64 + sch];
  }
  __syncthreads();
  short8 qf[2];
  qf[0] = *(const short8*)&Qs[(wave * 16 + col) * 72 + quad * 8];
  qf[1] = *(const short8*)&Qs[(wave * 16 + col) * 72 + 32 + quad * 8];

  f32x4 oacc[4];
#pragma unroll
  for (int nd = 0; nd < 4; nd++) oacc[nd] = (f32x4){0.f, 0.f, 0.f, 0.f};
  float m_s = -3.0e38f, l_s = 0.f;

  // j-tile phase stagger: start at tile jt0 = it (all 16 phases live per slice)
  int jt0 = it & 15;
  int t0 = jt0 * 64;
  int t1 = ((jt0 + 1) & 15) * 64;

  // prologue: tile t0 -> LDS[0]; preS/mask(t0) -> regs; tile t1 K/V -> regs
  KV kvA, kvB;
  f32x4 preA[4], preB[4];
  i32x4 mkA[4], mkB[4];
  kvA.k0 = *(const u32x4*)&kbase[(size_t)(t0 + srow) * 64 + sch];
  kvA.k1 = *(const u32x4*)&kbase[(size_t)(t0 + srow + 32) * 64 + sch];
  kvA.v0 = *(const u32x4*)&vbase[(size_t)srow * 1024 + t0 + sch];
  kvA.v1 = *(const u32x4*)&vbase[(size_t)(srow + 32) * 1024 + t0 + sch];
  *(u32x4*)&KsB[0][srow * 72 + sch] = kvA.k0;
  *(u32x4*)&KsB[0][(srow + 32) * 72 + sch] = kvA.k1;
  *(u32x4*)&VsB[0][srow * 72 + sch] = kvA.v0;
  *(u32x4*)&VsB[0][(srow + 32) * 72 + sch] = kvA.v1;
#pragma unroll
  for (int ns = 0; ns < 4; ns++) {
    preA[ns] = __builtin_nontemporal_load(
        (const f32x4*)&pbase[(size_t)lrow * 1024 + t0 + ns * 16 + quad * 4]);
    mkA[ns] = *(const i32x4*)&mbase[(size_t)lrow * 1024 + t0 + ns * 16 + quad * 4];
  }
  kvB.k0 = *(const u32x4*)&kbase[(size_t)(t1 + srow) * 64 + sch];
  kvB.k1 = *(const u32x4*)&kbase[(size_t)(t1 + srow + 32) * 64 + sch];
  kvB.v0 = *(const u32x4*)&vbase[(size_t)srow * 1024 + t1 + sch];
  kvB.v1 = *(const u32x4*)&vbase[(size_t)(srow + 32) * 1024 + t1 + sch];
  __syncthreads();

  unsigned short* Ps = Qs;   // Qs dead after qf; Ps rows are wave-private
  for (int n = 0; n < 16; n += 2) {
    int ja = ((jt0 + n) & 15) * 64;
    int jb = ((jt0 + n + 1) & 15) * 64;
    int jc = ((jt0 + n + 2) & 15) * 64;
    int jd = ((jt0 + n + 3) & 15) * 64;
    attn_body(ja, jb, jc, (n) < 15, (n) < 14,
              KsB[0], VsB[0], KsB[1], VsB[1], preA, preB, mkA, mkB, kvB, kvA,
              qf, oacc, m_s, l_s, kbase, vbase, pbase, mbase, sbase,
              Ps, eKs, eBs, lrow, gi, srow, sch, col, quad, wave);
    attn_body(jb, jc, jd, (n + 1) < 15, (n + 1) < 14,
              KsB[1], VsB[1], KsB[0], VsB[0], preB, preA, mkB, mkA, kvA, kvB,
              qf, oacc, m_s, l_s, kbase, vbase, pbase, mbase, sbase,
              Ps, eKs, eBs, lrow, gi, srow, sch, col, quad, wave);
  }

  float inv = 1.0f / fmaxf(l_s, 1e-30f);
  unsigned short* zb = zpre + ((size_t)(b * 12 + h) * 1024 + i0 + lrow) * 64;
#pragma unroll
  for (int nd = 0; nd < 4; nd++) {
    union { unsigned short s[4]; u32x2 u; } zk;
#pragma unroll
    for (int r = 0; r < 4; r++) zk.s[r] = f2bf(oacc[nd][r] * inv);
    *(u32x2*)&zb[nd * 16 + quad * 4] = zk.u;
  }
}

// ---------------------------------------------------------------------------
// Kernel 5: output projection, 64x64 tiles -> 768 blocks (3/CU), pipelined.
__global__ __launch_bounds__(256, 3) void out_gemm_kernel(
    const unsigned short* __restrict__ zpre, const unsigned short* __restrict__ wot,
    const float* __restrict__ wob, float* __restrict__ zout) {
  __shared__ unsigned short SM[2][2][64 * 72];
  int bx = blockIdx.x;
  int mt = bx / 12, nt = bx - mt * 12;
  int m0 = mt * 64, n0 = nt * 64;
  int t = threadIdx.x;
  int wave = t >> 6, lane = t & 63;
  int wm = (wave >> 1) * 32, wn = (wave & 1) * 32;
  int col = lane & 15, quad = lane >> 4;
  int srow = t >> 3, sch = (t & 7) * 8;
  int gmA0 = m0 + srow, gmA1 = m0 + srow + 32;
  int bA0 = gmA0 >> 10, lA0 = gmA0 & 1023;
  int bA1 = gmA1 >> 10, lA1 = gmA1 & 1023;

  f32x4 acc[2][2];
#pragma unroll
  for (int i = 0; i < 2; i++)
#pragma unroll
    for (int j = 0; j < 2; j++) acc[i][j] = (f32x4){0.f, 0.f, 0.f, 0.f};

  u32x4 ra[2], rb[2];
  // prologue: tile0 -> LDS0 (hh=0), tile1 -> regs
  ra[0] = *(const u32x4*)&zpre[((size_t)(bA0 * 12 + 0) * 1024 + lA0) * 64 + sch];
  ra[1] = *(const u32x4*)&zpre[((size_t)(bA1 * 12 + 0) * 1024 + lA1) * 64 + sch];
  rb[0] = *(const u32x4*)&wot[(size_t)(n0 + srow) * 768 + sch];
  rb[1] = *(const u32x4*)&wot[(size_t)(n0 + srow + 32) * 768 + sch];
  *(u32x4*)&SM[0][0][srow * 72 + sch] = ra[0];
  *(u32x4*)&SM[0][0][(srow + 32) * 72 + sch] = ra[1];
  *(u32x4*)&SM[0][1][srow * 72 + sch] = rb[0];
  *(u32x4*)&SM[0][1][(srow + 32) * 72 + sch] = rb[1];
  ra[0] = *(const u32x4*)&zpre[((size_t)(bA0 * 12 + 1) * 1024 + lA0) * 64 + sch];
  ra[1] = *(const u32x4*)&zpre[((size_t)(bA1 * 12 + 1) * 1024 + lA1) * 64 + sch];
  rb[0] = *(const u32x4*)&wot[(size_t)(n0 + srow) * 768 + 64 + sch];
  rb[1] = *(const u32x4*)&wot[(size_t)(n0 + srow + 32) * 768 + 64 + sch];
  __syncthreads();

  for (int it = 0; it < 12; ++it) {
    const unsigned short* As = SM[it & 1][0];
    const unsigned short* Bs = SM[it & 1][1];
#pragma unroll
    for (int c = 0; c < 2; c++) {
      short8 af[2], bf[2];
#pragma unroll
      for (int i = 0; i < 2; i++) {
        af[i] = *(const short8*)&As[(wm + i * 16 + col) * 72 + c * 32 + quad * 8];
        bf[i] = *(const short8*)&Bs[(wn + i * 16 + col) * 72 + c * 32 + quad * 8];
      }
#pragma unroll
      for (int i = 0; i < 2; i++)
#pragma unroll
        for (int j = 0; j < 2; j++)
          acc[i][j] = __builtin_amdgcn_mfma_f32_16x16x32_bf16(af[i], bf[j], acc[i][j], 0, 0, 0);
    }
    if (it < 11) {
      unsigned short* An = SM[(it + 1) & 1][0];
      unsigned short* Bn = SM[(it + 1) & 1][1];
      *(u32x4*)&An[srow * 72 + sch] = ra[0];
      *(u32x4*)&An[(srow + 32) * 72 + sch] = ra[1];
      *(u32x4*)&Bn[srow * 72 + sch] = rb[0];
      *(u32x4*)&Bn[(srow + 32) * 72 + sch] = rb[1];
      if (it < 10) {
        int hh = it + 2;
        ra[0] = *(const u32x4*)&zpre[((size_t)(bA0 * 12 + hh) * 1024 + lA0) * 64 + sch];
        ra[1] = *(const u32x4*)&zpre[((size_t)(bA1 * 12 + hh) * 1024 + lA1) * 64 + sch];
        rb[0] = *(const u32x4*)&wot[(size_t)(n0 + srow) * 768 + hh * 64 + sch];
        rb[1] = *(const u32x4*)&wot[(size_t)(n0 + srow + 32) * 768 + hh * 64 + sch];
      }
      __syncthreads();
    }
  }
#pragma unroll
  for (int j = 0; j < 2; j++) {
    int gn = n0 + wn + j * 16 + col;
    float bsv = wob[gn];
#pragma unroll
    for (int i = 0; i < 2; i++) {
#pragma unroll
      for (int r = 0; r < 4; r++) {
        int gm = m0 + wm + i * 16 + quad * 4 + r;
        zout[(size_t)gm * 768 + gn] = acc[i][j][r] + bsv;
      }
    }
  }
}

// ---------------------------------------------------------------------------
extern "C" void kernel_launch(void* const* d_in, const int* in_sizes, int n_in,
                              void* d_out, int out_size, void* d_ws, size_t ws_size,
                              hipStream_t stream) {
  const float* qx   = (const float*)d_in[0];
  const float* kx   = (const float*)d_in[1];
  const float* vx   = (const float*)d_in[2];
  const float* WQ_w = (const float*)d_in[3];
  const float* WQ_b = (const float*)d_in[4];
  const float* WK_w = (const float*)d_in[5];
  const float* WK_b = (const float*)d_in[6];
  const float* WV_w = (const float*)d_in[7];
  const float* WV_b = (const float*)d_in[8];
  const float* WO_w = (const float*)d_in[9];
  const float* WO_b = (const float*)d_in[10];
  const float* embK = (const float*)d_in[11];
  const float* embB = (const float*)d_in[12];
  const float* preS = (const float*)d_in[13];
  const int* maskP  = (const int*)d_in[14];

  float* zout = (float*)d_out;                       // [4,1024,768]
  float* scores = zout + 3145728;                    // [4,12,1024,1024]
  unsigned short* xbf = (unsigned short*)scores;     // scratch overlay (dead before attn)

  char* ws = (char*)d_ws;
  unsigned short* wt  = (unsigned short*)(ws);               // 4x768x768 bf16
  unsigned short* qb  = (unsigned short*)(ws + 4718592);     // [B,H,L,64] bf16
  unsigned short* kb  = (unsigned short*)(ws + 11010048);    // [B,H,L,64]
  unsigned short* vtb = (unsigned short*)(ws + 17301504);    // [B,H,64,L]
  unsigned short* zp  = (unsigned short*)(ws + 23592960);    // [B,H,L,64]

  conv_x_kernel<<<9216, 256, 0, stream>>>(qx, kx, vx, xbf);
  conv_w_kernel<<<576, 256, 0, stream>>>(WQ_w, WK_w, WV_w, WO_w, wt);
  qkv_gemm_kernel<<<576, 256, 0, stream>>>(xbf, wt, WQ_b, WK_b, WV_b, qb, kb, vtb);
  attn_kernel<<<768, 256, 0, stream>>>(qb, kb, vtb, preS, maskP, embK, embB, scores, zp);
  out_gemm_kernel<<<192 * 4, 256, 0, stream>>>(zp, wt + 3 * 589824, WO_b, zout);
}

// Round 2
// 499.953 us; speedup vs baseline: 1.0099x; 1.0099x over previous
//
#include <hip/hip_runtime.h>
#include <stdint.h>

// Problem constants (B=4, L=1024, C=768, H=12, DK=64, MAXREL=7)
// Outputs: z [4,1024,768] fp32 then scores [4,12,1024,1024] fp32, concatenated.

typedef __attribute__((ext_vector_type(4))) float f32x4;
typedef __attribute__((ext_vector_type(4))) int   i32x4;
typedef __attribute__((ext_vector_type(8))) short short8;   // 8 bf16 (4 VGPRs) - MFMA A/B frag
typedef __attribute__((ext_vector_type(4))) unsigned int u32x4;
typedef __attribute__((ext_vector_type(2))) unsigned int u32x2;

__device__ __forceinline__ unsigned short f2bf(float f) {   // fp32 -> bf16, RNE
  unsigned int u = __float_as_uint(f);
  u += 0x7fffu + ((u >> 16) & 1u);
  return (unsigned short)(u >> 16);
}

// ---------------------------------------------------------------------------
// Kernel 1: qx,kx,vx fp32 -> bf16
__global__ __launch_bounds__(256) void conv_x_kernel(
    const float* __restrict__ qx, const float* __restrict__ kx,
    const float* __restrict__ vx, unsigned short* __restrict__ out) {
  int v = blockIdx.x * 256 + threadIdx.x;       // float4 index
  int mat = v / 786432;
  int r = v - mat * 786432;
  const float* src = (mat == 0) ? qx : (mat == 1) ? kx : vx;
  f32x4 x = ((const f32x4*)src)[r];
  union { unsigned short s[4]; u32x2 u; } o;
  o.s[0] = f2bf(x[0]); o.s[1] = f2bf(x[1]); o.s[2] = f2bf(x[2]); o.s[3] = f2bf(x[3]);
  ((u32x2*)out)[v] = o.u;
}

// ---------------------------------------------------------------------------
// Kernel 2: W [768k][768n] fp32 -> WT [768n][768k] bf16, for WQ,WK,WV,WO.
__global__ __launch_bounds__(256) void conv_w_kernel(
    const float* __restrict__ w0, const float* __restrict__ w1,
    const float* __restrict__ w2, const float* __restrict__ w3,
    unsigned short* __restrict__ out) {
  __shared__ float T[64][65];
  int bx = blockIdx.x;
  int mat = bx / 144; int t2 = bx - mat * 144;
  int kt = t2 / 12, nt = t2 - kt * 12;
  int k0 = kt * 64, n0 = nt * 64;
  const float* W = (mat == 0) ? w0 : (mat == 1) ? w1 : (mat == 2) ? w2 : w3;
  unsigned short* WT = out + (size_t)mat * 589824;
  int t = threadIdx.x;
  int lr = t >> 4;
  int lc = (t & 15) * 4;
#pragma unroll
  for (int p = 0; p < 4; p++) {
    int row = p * 16 + lr;
    f32x4 x = *(const f32x4*)&W[(size_t)(k0 + row) * 768 + n0 + lc];
    T[lc + 0][row] = x[0]; T[lc + 1][row] = x[1];
    T[lc + 2][row] = x[2]; T[lc + 3][row] = x[3];
  }
  __syncthreads();
#pragma unroll
  for (int p = 0; p < 4; p++) {
    int row = p * 16 + lr;
    union { unsigned short s[4]; u32x2 u; } o;
    o.s[0] = f2bf(T[row][lc + 0]); o.s[1] = f2bf(T[row][lc + 1]);
    o.s[2] = f2bf(T[row][lc + 2]); o.s[3] = f2bf(T[row][lc + 3]);
    *(u32x2*)&WT[(size_t)(n0 + row) * 768 + k0 + lc] = o.u;
  }
}

// ---------------------------------------------------------------------------
// Kernel 3: QKV projection GEMM, software-pipelined (1 barrier/iter, reg prefetch).
// mat 0 -> q [B,H,L,64]; mat 1 -> k [B,H,L,64]; mat 2 -> vT [B,H,64,L] via LDS
// transpose bounce (coalesced dwordx4 stores; the R1 scatter was ~16x L2 write amp).
__global__ __launch_bounds__(256, 2) void qkv_gemm_kernel(
    const unsigned short* __restrict__ xbf, const unsigned short* __restrict__ wt,
    const float* __restrict__ bq, const float* __restrict__ bk, const float* __restrict__ bv,
    unsigned short* __restrict__ qo, unsigned short* __restrict__ ko,
    unsigned short* __restrict__ vto) {
  __shared__ unsigned short SM[2][2][128 * 72];   // [buf][A/B]
  int bx = blockIdx.x;
  int mat = bx / 192; int rem = bx - mat * 192;
  int mt = rem / 6, nt = rem - mt * 6;
  int m0 = mt * 128, n0 = nt * 128;
  const unsigned short* A = xbf + (size_t)mat * 4096 * 768;
  const unsigned short* Bm = wt + (size_t)mat * 768 * 768;
  int t = threadIdx.x;
  int wave = t >> 6, lane = t & 63;
  int wm = (wave >> 1) * 64, wn = (wave & 1) * 64;
  int col = lane & 15, quad = lane >> 4;
  int srow = t >> 3;
  int sch = (t & 7) * 8;

  f32x4 acc[4][4];
#pragma unroll
  for (int i = 0; i < 4; i++)
#pragma unroll
    for (int j = 0; j < 4; j++) acc[i][j] = (f32x4){0.f, 0.f, 0.f, 0.f};

  u32x4 ra[4], rb[4];
  // prologue: tile 0 -> LDS0; tile 1 -> regs
#pragma unroll
  for (int p = 0; p < 4; p++) {
    ra[p] = *(const u32x4*)&A[(size_t)(m0 + srow + p * 32) * 768 + sch];
    rb[p] = *(const u32x4*)&Bm[(size_t)(n0 + srow + p * 32) * 768 + sch];
  }
#pragma unroll
  for (int p = 0; p < 4; p++) {
    *(u32x4*)&SM[0][0][(srow + p * 32) * 72 + sch] = ra[p];
    *(u32x4*)&SM[0][1][(srow + p * 32) * 72 + sch] = rb[p];
  }
#pragma unroll
  for (int p = 0; p < 4; p++) {
    ra[p] = *(const u32x4*)&A[(size_t)(m0 + srow + p * 32) * 768 + 64 + sch];
    rb[p] = *(const u32x4*)&Bm[(size_t)(n0 + srow + p * 32) * 768 + 64 + sch];
  }
  __syncthreads();

  for (int it = 0; it < 12; ++it) {
    const unsigned short* As = SM[it & 1][0];
    const unsigned short* Bs = SM[it & 1][1];
#pragma unroll
    for (int c = 0; c < 2; c++) {
      short8 af[4], bf[4];
#pragma unroll
      for (int i = 0; i < 4; i++) {
        af[i] = *(const short8*)&As[(wm + i * 16 + col) * 72 + c * 32 + quad * 8];
        bf[i] = *(const short8*)&Bs[(wn + i * 16 + col) * 72 + c * 32 + quad * 8];
      }
#pragma unroll
      for (int i = 0; i < 4; i++)
#pragma unroll
        for (int j = 0; j < 4; j++)
          acc[i][j] = __builtin_amdgcn_mfma_f32_16x16x32_bf16(af[i], bf[j], acc[i][j], 0, 0, 0);
    }
    if (it < 11) {
      unsigned short* An = SM[(it + 1) & 1][0];
      unsigned short* Bn = SM[(it + 1) & 1][1];
#pragma unroll
      for (int p = 0; p < 4; p++) {
        *(u32x4*)&An[(srow + p * 32) * 72 + sch] = ra[p];
        *(u32x4*)&Bn[(srow + p * 32) * 72 + sch] = rb[p];
      }
      if (it < 10) {
        int kk2 = (it + 2) * 64;
#pragma unroll
        for (int p = 0; p < 4; p++) {
          ra[p] = *(const u32x4*)&A[(size_t)(m0 + srow + p * 32) * 768 + kk2 + sch];
          rb[p] = *(const u32x4*)&Bm[(size_t)(n0 + srow + p * 32) * 768 + kk2 + sch];
        }
      }
      __syncthreads();
    }
  }

  if (mat != 2) {
    const float* bias = (mat == 0) ? bq : bk;
    unsigned short* dst = (mat == 0) ? qo : ko;
#pragma unroll
    for (int j = 0; j < 4; j++) {
      int gn = n0 + wn + j * 16 + col;
      float bsv = bias[gn];
      int h = gn >> 6, d = gn & 63;
#pragma unroll
      for (int i = 0; i < 4; i++) {
#pragma unroll
        for (int r = 0; r < 4; r++) {
          int gm = m0 + wm + i * 16 + quad * 4 + r;
          int b = gm >> 10, l = gm & 1023;
          dst[((size_t)(b * 12 + h) * 1024 + l) * 64 + d] = f2bf(acc[i][j][r] + bsv);
        }
      }
    }
  } else {
    // transpose bounce: Tr[n_local][m_local], stride 132 shorts (33792 B <= 36864 SM)
    unsigned short* Tr = &SM[0][0][0];
    __syncthreads();   // all waves done with SM reads (last iter used SM[1]; Tr spans SM[0])
#pragma unroll
    for (int j = 0; j < 4; j++) {
      int n = wn + j * 16 + col;
      float bsv = bv[n0 + n];
#pragma unroll
      for (int i = 0; i < 4; i++) {
        int m = wm + i * 16 + quad * 4;
        union { unsigned short s[4]; u32x2 u; } pk;
#pragma unroll
        for (int r = 0; r < 4; r++) pk.s[r] = f2bf(acc[i][j][r] + bsv);
        *(u32x2*)&Tr[(size_t)n * 132 + m] = pk.u;
      }
    }
    __syncthreads();
#pragma unroll
    for (int p = 0; p < 8; p++) {
      int row = (t >> 4) + p * 16;          // n_local 0..127
      int ch = (t & 15) * 8;                // m_local chunk
      u32x4 val = *(const u32x4*)&Tr[(size_t)row * 132 + ch];
      int gn = n0 + row;
      int h = gn >> 6, d = gn & 63;
      int gm = m0 + ch;
      int b = gm >> 10, l = gm & 1023;
      *(u32x4*)&vto[((size_t)(b * 12 + h) * 64 + d) * 1024 + l] = val;
    }
  }
}

// ---------------------------------------------------------------------------
// Kernel 4: fused attention, software-pipelined.
// One barrier/iter: double-buffered K/V LDS; K/V prefetched 2 iters ahead in
// regs; preS AND mask prefetched 1 iter ahead in regs.
// R3 vs R2: scores stores back to NORMAL cached stores. R2's nontemporal
// stores caused 1.5x write amp (204->300MB): each 128B line is filled by two
// consecutive 64B wave-store chunks; nt evicts eagerly before the pair merges.
// Kept from R2 (confirmed good: delivered BW 2.9->3.3 TB/s):
//  - j-tile phase stagger (jt0 = i-tile index) to spread concurrent traffic
//    over all 16 column phases (DRAM channel/bank conflict fix).
//  - mask prefetched 1 tile ahead.
//  - preS loads nontemporal (single-use stream, loads can't amplify).
struct KV { u32x4 k0, k1, v0, v1; };

__device__ __forceinline__ void attn_body(
    int j0, int j1, int j2, bool pf1, bool pf2,
    const unsigned short* KsC, const unsigned short* VsC,
    unsigned short* KsN, unsigned short* VsN,
    f32x4* preC, f32x4* preN, i32x4* mkC, i32x4* mkN, KV& kvW, KV& kvF,
    const short8* qf, f32x4* oacc, float& m_s, float& l_s,
    const unsigned short* kbase, const unsigned short* vbase,
    const float* pbase, const int* mbase, float* sbase,
    unsigned short* Ps, const float* eK, const float* eB,
    int lrow, int gi, int srow, int sch, int col, int quad, int wave) {
  // issue preS + mask loads (tile j1)
  if (pf1) {
#pragma unroll
    for (int ns = 0; ns < 4; ns++) {
      preN[ns] = __builtin_nontemporal_load(
          (const f32x4*)&pbase[(size_t)lrow * 1024 + j1 + ns * 16 + quad * 4]);
      mkN[ns] = *(const i32x4*)&mbase[(size_t)lrow * 1024 + j1 + ns * 16 + quad * 4];
    }
  }
  // issue K/V loads (tile j2)
  if (pf2) {
    kvF.k0 = *(const u32x4*)&kbase[(size_t)(j2 + srow) * 64 + sch];
    kvF.k1 = *(const u32x4*)&kbase[(size_t)(j2 + srow + 32) * 64 + sch];
    kvF.v0 = *(const u32x4*)&vbase[(size_t)srow * 1024 + j2 + sch];
    kvF.v1 = *(const u32x4*)&vbase[(size_t)(srow + 32) * 1024 + j2 + sch];
  }
  // S^T tile: rows j (quad*4+reg), cols i (lane&15)
  f32x4 sacc[4];
#pragma unroll
  for (int ns = 0; ns < 4; ns++) sacc[ns] = (f32x4){0.f, 0.f, 0.f, 0.f};
#pragma unroll
  for (int c = 0; c < 2; c++) {
#pragma unroll
    for (int ns = 0; ns < 4; ns++) {
      short8 kf = *(const short8*)&KsC[(ns * 16 + col) * 72 + c * 32 + quad * 8];
      sacc[ns] = __builtin_amdgcn_mfma_f32_16x16x32_bf16(kf, qf[c], sacc[ns], 0, 0, 0);
    }
  }
  // epilogue: scale, rel-pos, preScores, mask, write scores
  float sv[4][4];
#pragma unroll
  for (int ns = 0; ns < 4; ns++) {
    int gj0 = j0 + ns * 16 + quad * 4;
    f32x4 sout;
#pragma unroll
    for (int r = 0; r < 4; r++) {
      int dd = gi - (gj0 + r); dd = dd < 0 ? -dd : dd;
      int idx;
      if (dd <= 7) idx = dd;
      else { idx = 38 - __clz(dd - 7); idx = idx > 14 ? 14 : idx; }  // exact floor(7+log2)
      float s = sacc[ns][r] * 0.125f * eK[idx] + eB[idx] + preC[ns][r];
      if (mkC[ns][r] == 0) s = -32768.0f;
      sout[r] = s; sv[ns][r] = s;
    }
    *(f32x4*)&sbase[(size_t)lrow * 1024 + gj0] = sout;
  }
  // online softmax
  float mx = sv[0][0];
#pragma unroll
  for (int ns = 0; ns < 4; ns++)
#pragma unroll
    for (int r = 0; r < 4; r++) mx = fmaxf(mx, sv[ns][r]);
  mx = fmaxf(mx, __shfl_xor(mx, 16));
  mx = fmaxf(mx, __shfl_xor(mx, 32));
  float mn = fmaxf(m_s, mx);
  float alpha = __expf(m_s - mn);
  float rs = 0.f;
#pragma unroll
  for (int ns = 0; ns < 4; ns++)
#pragma unroll
    for (int r = 0; r < 4; r++) { float p = __expf(sv[ns][r] - mn); sv[ns][r] = p; rs += p; }
  rs += __shfl_xor(rs, 16); rs += __shfl_xor(rs, 32);
  l_s = l_s * alpha + rs;
  m_s = mn;
#pragma unroll
  for (int nd = 0; nd < 4; nd++)
#pragma unroll
    for (int r = 0; r < 4; r++) oacc[nd][r] *= alpha;
  // P tile -> LDS (wave-private rows; same-wave RAW, compiler inserts lgkmcnt)
#pragma unroll
  for (int ns = 0; ns < 4; ns++) {
    union { unsigned short s[4]; u32x2 u; } pk;
#pragma unroll
    for (int r = 0; r < 4; r++) pk.s[r] = f2bf(sv[ns][r]);
    *(u32x2*)&Ps[(size_t)lrow * 72 + ns * 16 + quad * 4] = pk.u;
  }
  // Z^T += V^T * P^T
#pragma unroll
  for (int c2 = 0; c2 < 2; c2++) {
    short8 pf = *(const short8*)&Ps[(wave * 16 + col) * 72 + c2 * 32 + quad * 8];
#pragma unroll
    for (int nd = 0; nd < 4; nd++) {
      short8 vf = *(const short8*)&VsC[(nd * 16 + col) * 72 + c2 * 32 + quad * 8];
      oacc[nd] = __builtin_amdgcn_mfma_f32_16x16x32_bf16(vf, pf, oacc[nd], 0, 0, 0);
    }
  }
  // stage next tile -> alternate buffers; single barrier per iteration
  if (pf1) {
    *(u32x4*)&KsN[srow * 72 + sch] = kvW.k0;
    *(u32x4*)&KsN[(srow + 32) * 72 + sch] = kvW.k1;
    *(u32x4*)&VsN[srow * 72 + sch] = kvW.v0;
    *(u32x4*)&VsN[(srow + 32) * 72 + sch] = kvW.v1;
    __syncthreads();
  }
}

__global__ __launch_bounds__(256, 3) void attn_kernel(
    const unsigned short* __restrict__ q, const unsigned short* __restrict__ k,
    const unsigned short* __restrict__ vt, const float* __restrict__ preS,
    const int* __restrict__ maskP, const float* __restrict__ embK,
    const float* __restrict__ embB, float* __restrict__ scores,
    unsigned short* __restrict__ zpre) {
  __shared__ unsigned short Qs[64 * 72];        // aliased as Ps after qf read (wave-private rows)
  __shared__ unsigned short KsB[2][64 * 72];
  __shared__ unsigned short VsB[2][64 * 72];
  __shared__ float eKs[16], eBs[16];
  int bx = blockIdx.x;
  int slice = bx % 48, it = bx / 48;
  int b = slice / 12, h = slice - b * 12;
  int i0 = it * 64;
  int t = threadIdx.x, wave = t >> 6, lane = t & 63;
  int col = lane & 15, quad = lane >> 4;
  int srow = t >> 3, sch = (t & 7) * 8;

  if (t < 15) { eKs[t] = embK[t * 12 + h]; eBs[t] = embB[t * 12 + h]; }

  const unsigned short* qbase = q + ((size_t)(b * 12 + h) * 1024 + i0) * 64;
  const unsigned short* kbase = k + (size_t)(b * 12 + h) * 1024 * 64;
  const unsigned short* vbase = vt + (size_t)(b * 12 + h) * 64 * 1024;
  const float* pbase = preS + ((size_t)(b * 12 + h) * 1024 + i0) * 1024;
  const int* mbase = maskP + ((size_t)b * 1024 + i0) * 1024;
  float* sbase = scores + ((size_t)(b * 12 + h) * 1024 + i0) * 1024;
  int lrow = wave * 16 + col;
  int gi = i0 + lrow;

#pragma unroll
  for (int p = 0; p < 2; p++) {
    int row = srow + p * 32;
    *(u32x4*)&Qs[row * 72 + sch] = *(const u32x4*)&qbase[(size_t)row * 64 + sch];
  }
  __syncthreads();
  short8 qf[2];
  qf[0] = *(const short8*)&Qs[(wave * 16 + col) * 72 + quad * 8];
  qf[1] = *(const short8*)&Qs[(wave * 16 + col) * 72 + 32 + quad * 8];

  f32x4 oacc[4];
#pragma unroll
  for (int nd = 0; nd < 4; nd++) oacc[nd] = (f32x4){0.f, 0.f, 0.f, 0.f};
  float m_s = -3.0e38f, l_s = 0.f;

  // j-tile phase stagger: start at tile jt0 = it (all 16 phases live per slice)
  int jt0 = it & 15;
  int t0 = jt0 * 64;
  int t1 = ((jt0 + 1) & 15) * 64;

  // prologue: tile t0 -> LDS[0]; preS/mask(t0) -> regs; tile t1 K/V -> regs
  KV kvA, kvB;
  f32x4 preA[4], preB[4];
  i32x4 mkA[4], mkB[4];
  kvA.k0 = *(const u32x4*)&kbase[(size_t)(t0 + srow) * 64 + sch];
  kvA.k1 = *(const u32x4*)&kbase[(size_t)(t0 + srow + 32) * 64 + sch];
  kvA.v0 = *(const u32x4*)&vbase[(size_t)srow * 1024 + t0 + sch];
  kvA.v1 = *(const u32x4*)&vbase[(size_t)(srow + 32) * 1024 + t0 + sch];
  *(u32x4*)&KsB[0][srow * 72 + sch] = kvA.k0;
  *(u32x4*)&KsB[0][(srow + 32) * 72 + sch] = kvA.k1;
  *(u32x4*)&VsB[0][srow * 72 + sch] = kvA.v0;
  *(u32x4*)&VsB[0][(srow + 32) * 72 + sch] = kvA.v1;
#pragma unroll
  for (int ns = 0; ns < 4; ns++) {
    preA[ns] = __builtin_nontemporal_load(
        (const f32x4*)&pbase[(size_t)lrow * 1024 + t0 + ns * 16 + quad * 4]);
    mkA[ns] = *(const i32x4*)&mbase[(size_t)lrow * 1024 + t0 + ns * 16 + quad * 4];
  }
  kvB.k0 = *(const u32x4*)&kbase[(size_t)(t1 + srow) * 64 + sch];
  kvB.k1 = *(const u32x4*)&kbase[(size_t)(t1 + srow + 32) * 64 + sch];
  kvB.v0 = *(const u32x4*)&vbase[(size_t)srow * 1024 + t1 + sch];
  kvB.v1 = *(const u32x4*)&vbase[(size_t)(srow + 32) * 1024 + t1 + sch];
  __syncthreads();

  unsigned short* Ps = Qs;   // Qs dead after qf; Ps rows are wave-private
  for (int n = 0; n < 16; n += 2) {
    int ja = ((jt0 + n) & 15) * 64;
    int jb = ((jt0 + n + 1) & 15) * 64;
    int jc = ((jt0 + n + 2) & 15) * 64;
    int jd = ((jt0 + n + 3) & 15) * 64;
    attn_body(ja, jb, jc, (n) < 15, (n) < 14,
              KsB[0], VsB[0], KsB[1], VsB[1], preA, preB, mkA, mkB, kvB, kvA,
              qf, oacc, m_s, l_s, kbase, vbase, pbase, mbase, sbase,
              Ps, eKs, eBs, lrow, gi, srow, sch, col, quad, wave);
    attn_body(jb, jc, jd, (n + 1) < 15, (n + 1) < 14,
              KsB[1], VsB[1], KsB[0], VsB[0], preB, preA, mkB, mkA, kvA, kvB,
              qf, oacc, m_s, l_s, kbase, vbase, pbase, mbase, sbase,
              Ps, eKs, eBs, lrow, gi, srow, sch, col, quad, wave);
  }

  float inv = 1.0f / fmaxf(l_s, 1e-30f);
  unsigned short* zb = zpre + ((size_t)(b * 12 + h) * 1024 + i0 + lrow) * 64;
#pragma unroll
  for (int nd = 0; nd < 4; nd++) {
    union { unsigned short s[4]; u32x2 u; } zk;
#pragma unroll
    for (int r = 0; r < 4; r++) zk.s[r] = f2bf(oacc[nd][r] * inv);
    *(u32x2*)&zb[nd * 16 + quad * 4] = zk.u;
  }
}

// ---------------------------------------------------------------------------
// Kernel 5: output projection, 64x64 tiles -> 768 blocks (3/CU), pipelined.
__global__ __launch_bounds__(256, 3) void out_gemm_kernel(
    const unsigned short* __restrict__ zpre, const unsigned short* __restrict__ wot,
    const float* __restrict__ wob, float* __restrict__ zout) {
  __shared__ unsigned short SM[2][2][64 * 72];
  int bx = blockIdx.x;
  int mt = bx / 12, nt = bx - mt * 12;
  int m0 = mt * 64, n0 = nt * 64;
  int t = threadIdx.x;
  int wave = t >> 6, lane = t & 63;
  int wm = (wave >> 1) * 32, wn = (wave & 1) * 32;
  int col = lane & 15, quad = lane >> 4;
  int srow = t >> 3, sch = (t & 7) * 8;
  int gmA0 = m0 + srow, gmA1 = m0 + srow + 32;
  int bA0 = gmA0 >> 10, lA0 = gmA0 & 1023;
  int bA1 = gmA1 >> 10, lA1 = gmA1 & 1023;

  f32x4 acc[2][2];
#pragma unroll
  for (int i = 0; i < 2; i++)
#pragma unroll
    for (int j = 0; j < 2; j++) acc[i][j] = (f32x4){0.f, 0.f, 0.f, 0.f};

  u32x4 ra[2], rb[2];
  // prologue: tile0 -> LDS0 (hh=0), tile1 -> regs
  ra[0] = *(const u32x4*)&zpre[((size_t)(bA0 * 12 + 0) * 1024 + lA0) * 64 + sch];
  ra[1] = *(const u32x4*)&zpre[((size_t)(bA1 * 12 + 0) * 1024 + lA1) * 64 + sch];
  rb[0] = *(const u32x4*)&wot[(size_t)(n0 + srow) * 768 + sch];
  rb[1] = *(const u32x4*)&wot[(size_t)(n0 + srow + 32) * 768 + sch];
  *(u32x4*)&SM[0][0][srow * 72 + sch] = ra[0];
  *(u32x4*)&SM[0][0][(srow + 32) * 72 + sch] = ra[1];
  *(u32x4*)&SM[0][1][srow * 72 + sch] = rb[0];
  *(u32x4*)&SM[0][1][(srow + 32) * 72 + sch] = rb[1];
  ra[0] = *(const u32x4*)&zpre[((size_t)(bA0 * 12 + 1) * 1024 + lA0) * 64 + sch];
  ra[1] = *(const u32x4*)&zpre[((size_t)(bA1 * 12 + 1) * 1024 + lA1) * 64 + sch];
  rb[0] = *(const u32x4*)&wot[(size_t)(n0 + srow) * 768 + 64 + sch];
  rb[1] = *(const u32x4*)&wot[(size_t)(n0 + srow + 32) * 768 + 64 + sch];
  __syncthreads();

  for (int it = 0; it < 12; ++it) {
    const unsigned short* As = SM[it & 1][0];
    const unsigned short* Bs = SM[it & 1][1];
#pragma unroll
    for (int c = 0; c < 2; c++) {
      short8 af[2], bf[2];
#pragma unroll
      for (int i = 0; i < 2; i++) {
        af[i] = *(const short8*)&As[(wm + i * 16 + col) * 72 + c * 32 + quad * 8];
        bf[i] = *(const short8*)&Bs[(wn + i * 16 + col) * 72 + c * 32 + quad * 8];
      }
#pragma unroll
      for (int i = 0; i < 2; i++)
#pragma unroll
        for (int j = 0; j < 2; j++)
          acc[i][j] = __builtin_amdgcn_mfma_f32_16x16x32_bf16(af[i], bf[j], acc[i][j], 0, 0, 0);
    }
    if (it < 11) {
      unsigned short* An = SM[(it + 1) & 1][0];
      unsigned short* Bn = SM[(it + 1) & 1][1];
      *(u32x4*)&An[srow * 72 + sch] = ra[0];
      *(u32x4*)&An[(srow + 32) * 72 + sch] = ra[1];
      *(u32x4*)&Bn[srow * 72 + sch] = rb[0];
      *(u32x4*)&Bn[(srow + 32) * 72 + sch] = rb[1];
      if (it < 10) {
        int hh = it + 2;
        ra[0] = *(const u32x4*)&zpre[((size_t)(bA0 * 12 + hh) * 1024 + lA0) * 64 + sch];
        ra[1] = *(const u32x4*)&zpre[((size_t)(bA1 * 12 + hh) * 1024 + lA1) * 64 + sch];
        rb[0] = *(const u32x4*)&wot[(size_t)(n0 + srow) * 768 + hh * 64 + sch];
        rb[1] = *(const u32x4*)&wot[(size_t)(n0 + srow + 32) * 768 + hh * 64 + sch];
      }
      __syncthreads();
    }
  }
#pragma unroll
  for (int j = 0; j < 2; j++) {
    int gn = n0 + wn + j * 16 + col;
    float bsv = wob[gn];
#pragma unroll
    for (int i = 0; i < 2; i++) {
#pragma unroll
      for (int r = 0; r < 4; r++) {
        int gm = m0 + wm + i * 16 + quad * 4 + r;
        zout[(size_t)gm * 768 + gn] = acc[i][j][r] + bsv;
      }
    }
  }
}

// ---------------------------------------------------------------------------
extern "C" void kernel_launch(void* const* d_in, const int* in_sizes, int n_in,
                              void* d_out, int out_size, void* d_ws, size_t ws_size,
                              hipStream_t stream) {
  const float* qx   = (const float*)d_in[0];
  const float* kx   = (const float*)d_in[1];
  const float* vx   = (const float*)d_in[2];
  const float* WQ_w = (const float*)d_in[3];
  const float* WQ_b = (const float*)d_in[4];
  const float* WK_w = (const float*)d_in[5];
  const float* WK_b = (const float*)d_in[6];
  const float* WV_w = (const float*)d_in[7];
  const float* WV_b = (const float*)d_in[8];
  const float* WO_w = (const float*)d_in[9];
  const float* WO_b = (const float*)d_in[10];
  const float* embK = (const float*)d_in[11];
  const float* embB = (const float*)d_in[12];
  const float* preS = (const float*)d_in[13];
  const int* maskP  = (const int*)d_in[14];

  float* zout = (float*)d_out;                       // [4,1024,768]
  float* scores = zout + 3145728;                    // [4,12,1024,1024]
  unsigned short* xbf = (unsigned short*)scores;     // scratch overlay (dead before attn)

  char* ws = (char*)d_ws;
  unsigned short* wt  = (unsigned short*)(ws);               // 4x768x768 bf16
  unsigned short* qb  = (unsigned short*)(ws + 4718592);     // [B,H,L,64] bf16
  unsigned short* kb  = (unsigned short*)(ws + 11010048);    // [B,H,L,64]
  unsigned short* vtb = (unsigned short*)(ws + 17301504);    // [B,H,64,L]
  unsigned short* zp  = (unsigned short*)(ws + 23592960);    // [B,H,L,64]

  conv_x_kernel<<<9216, 256, 0, stream>>>(qx, kx, vx, xbf);
  conv_w_kernel<<<576, 256, 0, stream>>>(WQ_w, WK_w, WV_w, WO_w, wt);
  qkv_gemm_kernel<<<576, 256, 0, stream>>>(xbf, wt, WQ_b, WK_b, WV_b, qb, kb, vtb);
  attn_kernel<<<768, 256, 0, stream>>>(qb, kb, vtb, preS, maskP, embK, embB, scores, zp);
  out_gemm_kernel<<<192 * 4, 256, 0, stream>>>(zp, wt + 3 * 589824, WO_b, zout);
}

// Round 3
// 497.611 us; speedup vs baseline: 1.0147x; 1.0047x over previous
//
#include <hip/hip_runtime.h>
#include <stdint.h>

// Problem constants (B=4, L=1024, C=768, H=12, DK=64, MAXREL=7)
// Outputs: z [4,1024,768] fp32 then scores [4,12,1024,1024] fp32, concatenated.

typedef __attribute__((ext_vector_type(4))) float f32x4;
typedef __attribute__((ext_vector_type(4))) int   i32x4;
typedef __attribute__((ext_vector_type(8))) short short8;   // 8 bf16 (4 VGPRs) - MFMA A/B frag
typedef __attribute__((ext_vector_type(4))) unsigned int u32x4;
typedef __attribute__((ext_vector_type(2))) unsigned int u32x2;

__device__ __forceinline__ unsigned short f2bf(float f) {   // fp32 -> bf16, RNE
  unsigned int u = __float_as_uint(f);
  u += 0x7fffu + ((u >> 16) & 1u);
  return (unsigned short)(u >> 16);
}

// ---------------------------------------------------------------------------
// Kernel 1: qx,kx,vx fp32 -> bf16
__global__ __launch_bounds__(256) void conv_x_kernel(
    const float* __restrict__ qx, const float* __restrict__ kx,
    const float* __restrict__ vx, unsigned short* __restrict__ out) {
  int v = blockIdx.x * 256 + threadIdx.x;       // float4 index
  int mat = v / 786432;
  int r = v - mat * 786432;
  const float* src = (mat == 0) ? qx : (mat == 1) ? kx : vx;
  f32x4 x = ((const f32x4*)src)[r];
  union { unsigned short s[4]; u32x2 u; } o;
  o.s[0] = f2bf(x[0]); o.s[1] = f2bf(x[1]); o.s[2] = f2bf(x[2]); o.s[3] = f2bf(x[3]);
  ((u32x2*)out)[v] = o.u;
}

// ---------------------------------------------------------------------------
// Kernel 2: W [768k][768n] fp32 -> WT [768n][768k] bf16, for WQ,WK,WV,WO.
__global__ __launch_bounds__(256) void conv_w_kernel(
    const float* __restrict__ w0, const float* __restrict__ w1,
    const float* __restrict__ w2, const float* __restrict__ w3,
    unsigned short* __restrict__ out) {
  __shared__ float T[64][65];
  int bx = blockIdx.x;
  int mat = bx / 144; int t2 = bx - mat * 144;
  int kt = t2 / 12, nt = t2 - kt * 12;
  int k0 = kt * 64, n0 = nt * 64;
  const float* W = (mat == 0) ? w0 : (mat == 1) ? w1 : (mat == 2) ? w2 : w3;
  unsigned short* WT = out + (size_t)mat * 589824;
  int t = threadIdx.x;
  int lr = t >> 4;
  int lc = (t & 15) * 4;
#pragma unroll
  for (int p = 0; p < 4; p++) {
    int row = p * 16 + lr;
    f32x4 x = *(const f32x4*)&W[(size_t)(k0 + row) * 768 + n0 + lc];
    T[lc + 0][row] = x[0]; T[lc + 1][row] = x[1];
    T[lc + 2][row] = x[2]; T[lc + 3][row] = x[3];
  }
  __syncthreads();
#pragma unroll
  for (int p = 0; p < 4; p++) {
    int row = p * 16 + lr;
    union { unsigned short s[4]; u32x2 u; } o;
    o.s[0] = f2bf(T[row][lc + 0]); o.s[1] = f2bf(T[row][lc + 1]);
    o.s[2] = f2bf(T[row][lc + 2]); o.s[3] = f2bf(T[row][lc + 3]);
    *(u32x2*)&WT[(size_t)(n0 + row) * 768 + k0 + lc] = o.u;
  }
}

// ---------------------------------------------------------------------------
// Kernel 3: QKV projection GEMM, software-pipelined (1 barrier/iter, reg prefetch).
// mat 0 -> q [B,H,L,64]; mat 1 -> k [B,H,L,64]; mat 2 -> vT [B,H,64,L] via LDS
// transpose bounce (coalesced dwordx4 stores; the R1 scatter was ~16x L2 write amp).
__global__ __launch_bounds__(256, 2) void qkv_gemm_kernel(
    const unsigned short* __restrict__ xbf, const unsigned short* __restrict__ wt,
    const float* __restrict__ bq, const float* __restrict__ bk, const float* __restrict__ bv,
    unsigned short* __restrict__ qo, unsigned short* __restrict__ ko,
    unsigned short* __restrict__ vto) {
  __shared__ unsigned short SM[2][2][128 * 72];   // [buf][A/B]
  int bx = blockIdx.x;
  int mat = bx / 192; int rem = bx - mat * 192;
  int mt = rem / 6, nt = rem - mt * 6;
  int m0 = mt * 128, n0 = nt * 128;
  const unsigned short* A = xbf + (size_t)mat * 4096 * 768;
  const unsigned short* Bm = wt + (size_t)mat * 768 * 768;
  int t = threadIdx.x;
  int wave = t >> 6, lane = t & 63;
  int wm = (wave >> 1) * 64, wn = (wave & 1) * 64;
  int col = lane & 15, quad = lane >> 4;
  int srow = t >> 3;
  int sch = (t & 7) * 8;

  f32x4 acc[4][4];
#pragma unroll
  for (int i = 0; i < 4; i++)
#pragma unroll
    for (int j = 0; j < 4; j++) acc[i][j] = (f32x4){0.f, 0.f, 0.f, 0.f};

  u32x4 ra[4], rb[4];
  // prologue: tile 0 -> LDS0; tile 1 -> regs
#pragma unroll
  for (int p = 0; p < 4; p++) {
    ra[p] = *(const u32x4*)&A[(size_t)(m0 + srow + p * 32) * 768 + sch];
    rb[p] = *(const u32x4*)&Bm[(size_t)(n0 + srow + p * 32) * 768 + sch];
  }
#pragma unroll
  for (int p = 0; p < 4; p++) {
    *(u32x4*)&SM[0][0][(srow + p * 32) * 72 + sch] = ra[p];
    *(u32x4*)&SM[0][1][(srow + p * 32) * 72 + sch] = rb[p];
  }
#pragma unroll
  for (int p = 0; p < 4; p++) {
    ra[p] = *(const u32x4*)&A[(size_t)(m0 + srow + p * 32) * 768 + 64 + sch];
    rb[p] = *(const u32x4*)&Bm[(size_t)(n0 + srow + p * 32) * 768 + 64 + sch];
  }
  __syncthreads();

  for (int it = 0; it < 12; ++it) {
    const unsigned short* As = SM[it & 1][0];
    const unsigned short* Bs = SM[it & 1][1];
#pragma unroll
    for (int c = 0; c < 2; c++) {
      short8 af[4], bf[4];
#pragma unroll
      for (int i = 0; i < 4; i++) {
        af[i] = *(const short8*)&As[(wm + i * 16 + col) * 72 + c * 32 + quad * 8];
        bf[i] = *(const short8*)&Bs[(wn + i * 16 + col) * 72 + c * 32 + quad * 8];
      }
#pragma unroll
      for (int i = 0; i < 4; i++)
#pragma unroll
        for (int j = 0; j < 4; j++)
          acc[i][j] = __builtin_amdgcn_mfma_f32_16x16x32_bf16(af[i], bf[j], acc[i][j], 0, 0, 0);
    }
    if (it < 11) {
      unsigned short* An = SM[(it + 1) & 1][0];
      unsigned short* Bn = SM[(it + 1) & 1][1];
#pragma unroll
      for (int p = 0; p < 4; p++) {
        *(u32x4*)&An[(srow + p * 32) * 72 + sch] = ra[p];
        *(u32x4*)&Bn[(srow + p * 32) * 72 + sch] = rb[p];
      }
      if (it < 10) {
        int kk2 = (it + 2) * 64;
#pragma unroll
        for (int p = 0; p < 4; p++) {
          ra[p] = *(const u32x4*)&A[(size_t)(m0 + srow + p * 32) * 768 + kk2 + sch];
          rb[p] = *(const u32x4*)&Bm[(size_t)(n0 + srow + p * 32) * 768 + kk2 + sch];
        }
      }
      __syncthreads();
    }
  }

  if (mat != 2) {
    const float* bias = (mat == 0) ? bq : bk;
    unsigned short* dst = (mat == 0) ? qo : ko;
#pragma unroll
    for (int j = 0; j < 4; j++) {
      int gn = n0 + wn + j * 16 + col;
      float bsv = bias[gn];
      int h = gn >> 6, d = gn & 63;
#pragma unroll
      for (int i = 0; i < 4; i++) {
#pragma unroll
        for (int r = 0; r < 4; r++) {
          int gm = m0 + wm + i * 16 + quad * 4 + r;
          int b = gm >> 10, l = gm & 1023;
          dst[((size_t)(b * 12 + h) * 1024 + l) * 64 + d] = f2bf(acc[i][j][r] + bsv);
        }
      }
    }
  } else {
    // transpose bounce: Tr[n_local][m_local], stride 132 shorts (33792 B <= 36864 SM)
    unsigned short* Tr = &SM[0][0][0];
    __syncthreads();   // all waves done with SM reads (last iter used SM[1]; Tr spans SM[0])
#pragma unroll
    for (int j = 0; j < 4; j++) {
      int n = wn + j * 16 + col;
      float bsv = bv[n0 + n];
#pragma unroll
      for (int i = 0; i < 4; i++) {
        int m = wm + i * 16 + quad * 4;
        union { unsigned short s[4]; u32x2 u; } pk;
#pragma unroll
        for (int r = 0; r < 4; r++) pk.s[r] = f2bf(acc[i][j][r] + bsv);
        *(u32x2*)&Tr[(size_t)n * 132 + m] = pk.u;
      }
    }
    __syncthreads();
#pragma unroll
    for (int p = 0; p < 8; p++) {
      int row = (t >> 4) + p * 16;          // n_local 0..127
      int ch = (t & 15) * 8;                // m_local chunk
      u32x4 val = *(const u32x4*)&Tr[(size_t)row * 132 + ch];
      int gn = n0 + row;
      int h = gn >> 6, d = gn & 63;
      int gm = m0 + ch;
      int b = gm >> 10, l = gm & 1023;
      *(u32x4*)&vto[((size_t)(b * 12 + h) * 64 + d) * 1024 + l] = val;
    }
  }
}

// ---------------------------------------------------------------------------
// Kernel 4: fused attention, software-pipelined.
// R4 vs R3:
//  - preS/mask prefetch DISTANCE 2 with the same two register buffer sets:
//    body n consumes tile n in the epilogue, then REFILLS the same regs with
//    tile n+2 (issue stays after last use via WAR; n,n+2 share parity so the
//    A/B alternation is preserved). Doubles outstanding bytes on the
//    HBM-critical preS stream (the wave-visible latency stall).
//  - preS loads back to normal cached (nt killed cross-dispatch L3 retention;
//    R0 FETCH=188 < preS size proved retention exists).
// Kept: j-tile phase stagger (jt0=it), cached scores stores, K/V 2-deep,
// double-buffered K/V LDS, 1 barrier/iter.
struct KV { u32x4 k0, k1, v0, v1; };

__device__ __forceinline__ void attn_body(
    int j0, int j2, bool stageNext, bool pf2,
    const unsigned short* KsC, const unsigned short* VsC,
    unsigned short* KsN, unsigned short* VsN,
    f32x4* preC, i32x4* mkC, KV& kvW, KV& kvF,
    const short8* qf, f32x4* oacc, float& m_s, float& l_s,
    const unsigned short* kbase, const unsigned short* vbase,
    const float* pbase, const int* mbase, float* sbase,
    unsigned short* Ps, const float* eK, const float* eB,
    int lrow, int gi, int srow, int sch, int col, int quad, int wave) {
  // issue K/V loads (tile j2 = n+2)
  if (pf2) {
    kvF.k0 = *(const u32x4*)&kbase[(size_t)(j2 + srow) * 64 + sch];
    kvF.k1 = *(const u32x4*)&kbase[(size_t)(j2 + srow + 32) * 64 + sch];
    kvF.v0 = *(const u32x4*)&vbase[(size_t)srow * 1024 + j2 + sch];
    kvF.v1 = *(const u32x4*)&vbase[(size_t)(srow + 32) * 1024 + j2 + sch];
  }
  // S^T tile: rows j (quad*4+reg), cols i (lane&15)
  f32x4 sacc[4];
#pragma unroll
  for (int ns = 0; ns < 4; ns++) sacc[ns] = (f32x4){0.f, 0.f, 0.f, 0.f};
#pragma unroll
  for (int c = 0; c < 2; c++) {
#pragma unroll
    for (int ns = 0; ns < 4; ns++) {
      short8 kf = *(const short8*)&KsC[(ns * 16 + col) * 72 + c * 32 + quad * 8];
      sacc[ns] = __builtin_amdgcn_mfma_f32_16x16x32_bf16(kf, qf[c], sacc[ns], 0, 0, 0);
    }
  }
  // epilogue: scale, rel-pos, preScores, mask, write scores (consumes preC/mkC)
  float sv[4][4];
#pragma unroll
  for (int ns = 0; ns < 4; ns++) {
    int gj0 = j0 + ns * 16 + quad * 4;
    f32x4 sout;
#pragma unroll
    for (int r = 0; r < 4; r++) {
      int dd = gi - (gj0 + r); dd = dd < 0 ? -dd : dd;
      int idx;
      if (dd <= 7) idx = dd;
      else { idx = 38 - __clz(dd - 7); idx = idx > 14 ? 14 : idx; }  // exact floor(7+log2)
      float s = sacc[ns][r] * 0.125f * eK[idx] + eB[idx] + preC[ns][r];
      if (mkC[ns][r] == 0) s = -32768.0f;
      sout[r] = s; sv[ns][r] = s;
    }
    *(f32x4*)&sbase[(size_t)lrow * 1024 + gj0] = sout;
  }
  // refill preC/mkC with tile n+2 (issues here, consumed 2 bodies later)
  if (pf2) {
#pragma unroll
    for (int ns = 0; ns < 4; ns++) {
      preC[ns] = *(const f32x4*)&pbase[(size_t)lrow * 1024 + j2 + ns * 16 + quad * 4];
      mkC[ns] = *(const i32x4*)&mbase[(size_t)lrow * 1024 + j2 + ns * 16 + quad * 4];
    }
  }
  // online softmax
  float mx = sv[0][0];
#pragma unroll
  for (int ns = 0; ns < 4; ns++)
#pragma unroll
    for (int r = 0; r < 4; r++) mx = fmaxf(mx, sv[ns][r]);
  mx = fmaxf(mx, __shfl_xor(mx, 16));
  mx = fmaxf(mx, __shfl_xor(mx, 32));
  float mn = fmaxf(m_s, mx);
  float alpha = __expf(m_s - mn);
  float rs = 0.f;
#pragma unroll
  for (int ns = 0; ns < 4; ns++)
#pragma unroll
    for (int r = 0; r < 4; r++) { float p = __expf(sv[ns][r] - mn); sv[ns][r] = p; rs += p; }
  rs += __shfl_xor(rs, 16); rs += __shfl_xor(rs, 32);
  l_s = l_s * alpha + rs;
  m_s = mn;
#pragma unroll
  for (int nd = 0; nd < 4; nd++)
#pragma unroll
    for (int r = 0; r < 4; r++) oacc[nd][r] *= alpha;
  // P tile -> LDS (wave-private rows; same-wave RAW, compiler inserts lgkmcnt)
#pragma unroll
  for (int ns = 0; ns < 4; ns++) {
    union { unsigned short s[4]; u32x2 u; } pk;
#pragma unroll
    for (int r = 0; r < 4; r++) pk.s[r] = f2bf(sv[ns][r]);
    *(u32x2*)&Ps[(size_t)lrow * 72 + ns * 16 + quad * 4] = pk.u;
  }
  // Z^T += V^T * P^T
#pragma unroll
  for (int c2 = 0; c2 < 2; c2++) {
    short8 pf = *(const short8*)&Ps[(wave * 16 + col) * 72 + c2 * 32 + quad * 8];
#pragma unroll
    for (int nd = 0; nd < 4; nd++) {
      short8 vf = *(const short8*)&VsC[(nd * 16 + col) * 72 + c2 * 32 + quad * 8];
      oacc[nd] = __builtin_amdgcn_mfma_f32_16x16x32_bf16(vf, pf, oacc[nd], 0, 0, 0);
    }
  }
  // stage tile n+1 -> alternate buffers; single barrier per iteration
  if (stageNext) {
    *(u32x4*)&KsN[srow * 72 + sch] = kvW.k0;
    *(u32x4*)&KsN[(srow + 32) * 72 + sch] = kvW.k1;
    *(u32x4*)&VsN[srow * 72 + sch] = kvW.v0;
    *(u32x4*)&VsN[(srow + 32) * 72 + sch] = kvW.v1;
    __syncthreads();
  }
}

__global__ __launch_bounds__(256, 3) void attn_kernel(
    const unsigned short* __restrict__ q, const unsigned short* __restrict__ k,
    const unsigned short* __restrict__ vt, const float* __restrict__ preS,
    const int* __restrict__ maskP, const float* __restrict__ embK,
    const float* __restrict__ embB, float* __restrict__ scores,
    unsigned short* __restrict__ zpre) {
  __shared__ unsigned short Qs[64 * 72];        // aliased as Ps after qf read (wave-private rows)
  __shared__ unsigned short KsB[2][64 * 72];
  __shared__ unsigned short VsB[2][64 * 72];
  __shared__ float eKs[16], eBs[16];
  int bx = blockIdx.x;
  int slice = bx % 48, it = bx / 48;
  int b = slice / 12, h = slice - b * 12;
  int i0 = it * 64;
  int t = threadIdx.x, wave = t >> 6, lane = t & 63;
  int col = lane & 15, quad = lane >> 4;
  int srow = t >> 3, sch = (t & 7) * 8;

  if (t < 15) { eKs[t] = embK[t * 12 + h]; eBs[t] = embB[t * 12 + h]; }

  const unsigned short* qbase = q + ((size_t)(b * 12 + h) * 1024 + i0) * 64;
  const unsigned short* kbase = k + (size_t)(b * 12 + h) * 1024 * 64;
  const unsigned short* vbase = vt + (size_t)(b * 12 + h) * 64 * 1024;
  const float* pbase = preS + ((size_t)(b * 12 + h) * 1024 + i0) * 1024;
  const int* mbase = maskP + ((size_t)b * 1024 + i0) * 1024;
  float* sbase = scores + ((size_t)(b * 12 + h) * 1024 + i0) * 1024;
  int lrow = wave * 16 + col;
  int gi = i0 + lrow;

#pragma unroll
  for (int p = 0; p < 2; p++) {
    int row = srow + p * 32;
    *(u32x4*)&Qs[row * 72 + sch] = *(const u32x4*)&qbase[(size_t)row * 64 + sch];
  }
  __syncthreads();
  short8 qf[2];
  qf[0] = *(const short8*)&Qs[(wave * 16 + col) * 72 + quad * 8];
  qf[1] = *(const short8*)&Qs[(wave * 16 + col) * 72 + 32 + quad * 8];

  f32x4 oacc[4];
#pragma unroll
  for (int nd = 0; nd < 4; nd++) oacc[nd] = (f32x4){0.f, 0.f, 0.f, 0.f};
  float m_s = -3.0e38f, l_s = 0.f;

  // j-tile phase stagger: start at tile jt0 = it (all 16 phases live per slice)
  int jt0 = it & 15;
  int t0 = jt0 * 64;
  int t1 = ((jt0 + 1) & 15) * 64;

  // prologue: tile t0 -> LDS[0]; preS/mask(t0,t1) -> regs; tile t1 K/V -> regs
  KV kvA, kvB;
  f32x4 preA[4], preB[4];
  i32x4 mkA[4], mkB[4];
  kvA.k0 = *(const u32x4*)&kbase[(size_t)(t0 + srow) * 64 + sch];
  kvA.k1 = *(const u32x4*)&kbase[(size_t)(t0 + srow + 32) * 64 + sch];
  kvA.v0 = *(const u32x4*)&vbase[(size_t)srow * 1024 + t0 + sch];
  kvA.v1 = *(const u32x4*)&vbase[(size_t)(srow + 32) * 1024 + t0 + sch];
  *(u32x4*)&KsB[0][srow * 72 + sch] = kvA.k0;
  *(u32x4*)&KsB[0][(srow + 32) * 72 + sch] = kvA.k1;
  *(u32x4*)&VsB[0][srow * 72 + sch] = kvA.v0;
  *(u32x4*)&VsB[0][(srow + 32) * 72 + sch] = kvA.v1;
#pragma unroll
  for (int ns = 0; ns < 4; ns++) {
    preA[ns] = *(const f32x4*)&pbase[(size_t)lrow * 1024 + t0 + ns * 16 + quad * 4];
    mkA[ns] = *(const i32x4*)&mbase[(size_t)lrow * 1024 + t0 + ns * 16 + quad * 4];
    preB[ns] = *(const f32x4*)&pbase[(size_t)lrow * 1024 + t1 + ns * 16 + quad * 4];
    mkB[ns] = *(const i32x4*)&mbase[(size_t)lrow * 1024 + t1 + ns * 16 + quad * 4];
  }
  kvB.k0 = *(const u32x4*)&kbase[(size_t)(t1 + srow) * 64 + sch];
  kvB.k1 = *(const u32x4*)&kbase[(size_t)(t1 + srow + 32) * 64 + sch];
  kvB.v0 = *(const u32x4*)&vbase[(size_t)srow * 1024 + t1 + sch];
  kvB.v1 = *(const u32x4*)&vbase[(size_t)(srow + 32) * 1024 + t1 + sch];
  __syncthreads();

  unsigned short* Ps = Qs;   // Qs dead after qf; Ps rows are wave-private
  for (int n = 0; n < 16; n += 2) {
    int ja = ((jt0 + n) & 15) * 64;
    int jb = ((jt0 + n + 1) & 15) * 64;
    int jc = ((jt0 + n + 2) & 15) * 64;
    int jd = ((jt0 + n + 3) & 15) * 64;
    attn_body(ja, jc, n < 15, n < 14,
              KsB[0], VsB[0], KsB[1], VsB[1], preA, mkA, kvB, kvA,
              qf, oacc, m_s, l_s, kbase, vbase, pbase, mbase, sbase,
              Ps, eKs, eBs, lrow, gi, srow, sch, col, quad, wave);
    attn_body(jb, jd, n + 1 < 15, n + 1 < 14,
              KsB[1], VsB[1], KsB[0], VsB[0], preB, mkB, kvA, kvB,
              qf, oacc, m_s, l_s, kbase, vbase, pbase, mbase, sbase,
              Ps, eKs, eBs, lrow, gi, srow, sch, col, quad, wave);
  }

  float inv = 1.0f / fmaxf(l_s, 1e-30f);
  unsigned short* zb = zpre + ((size_t)(b * 12 + h) * 1024 + i0 + lrow) * 64;
#pragma unroll
  for (int nd = 0; nd < 4; nd++) {
    union { unsigned short s[4]; u32x2 u; } zk;
#pragma unroll
    for (int r = 0; r < 4; r++) zk.s[r] = f2bf(oacc[nd][r] * inv);
    *(u32x2*)&zb[nd * 16 + quad * 4] = zk.u;
  }
}

// ---------------------------------------------------------------------------
// Kernel 5: output projection, 64x64 tiles -> 768 blocks (3/CU), pipelined.
__global__ __launch_bounds__(256, 3) void out_gemm_kernel(
    const unsigned short* __restrict__ zpre, const unsigned short* __restrict__ wot,
    const float* __restrict__ wob, float* __restrict__ zout) {
  __shared__ unsigned short SM[2][2][64 * 72];
  int bx = blockIdx.x;
  int mt = bx / 12, nt = bx - mt * 12;
  int m0 = mt * 64, n0 = nt * 64;
  int t = threadIdx.x;
  int wave = t >> 6, lane = t & 63;
  int wm = (wave >> 1) * 32, wn = (wave & 1) * 32;
  int col = lane & 15, quad = lane >> 4;
  int srow = t >> 3, sch = (t & 7) * 8;
  int gmA0 = m0 + srow, gmA1 = m0 + srow + 32;
  int bA0 = gmA0 >> 10, lA0 = gmA0 & 1023;
  int bA1 = gmA1 >> 10, lA1 = gmA1 & 1023;

  f32x4 acc[2][2];
#pragma unroll
  for (int i = 0; i < 2; i++)
#pragma unroll
    for (int j = 0; j < 2; j++) acc[i][j] = (f32x4){0.f, 0.f, 0.f, 0.f};

  u32x4 ra[2], rb[2];
  // prologue: tile0 -> LDS0 (hh=0), tile1 -> regs
  ra[0] = *(const u32x4*)&zpre[((size_t)(bA0 * 12 + 0) * 1024 + lA0) * 64 + sch];
  ra[1] = *(const u32x4*)&zpre[((size_t)(bA1 * 12 + 0) * 1024 + lA1) * 64 + sch];
  rb[0] = *(const u32x4*)&wot[(size_t)(n0 + srow) * 768 + sch];
  rb[1] = *(const u32x4*)&wot[(size_t)(n0 + srow + 32) * 768 + sch];
  *(u32x4*)&SM[0][0][srow * 72 + sch] = ra[0];
  *(u32x4*)&SM[0][0][(srow + 32) * 72 + sch] = ra[1];
  *(u32x4*)&SM[0][1][srow * 72 + sch] = rb[0];
  *(u32x4*)&SM[0][1][(srow + 32) * 72 + sch] = rb[1];
  ra[0] = *(const u32x4*)&zpre[((size_t)(bA0 * 12 + 1) * 1024 + lA0) * 64 + sch];
  ra[1] = *(const u32x4*)&zpre[((size_t)(bA1 * 12 + 1) * 1024 + lA1) * 64 + sch];
  rb[0] = *(const u32x4*)&wot[(size_t)(n0 + srow) * 768 + 64 + sch];
  rb[1] = *(const u32x4*)&wot[(size_t)(n0 + srow + 32) * 768 + 64 + sch];
  __syncthreads();

  for (int it = 0; it < 12; ++it) {
    const unsigned short* As = SM[it & 1][0];
    const unsigned short* Bs = SM[it & 1][1];
#pragma unroll
    for (int c = 0; c < 2; c++) {
      short8 af[2], bf[2];
#pragma unroll
      for (int i = 0; i < 2; i++) {
        af[i] = *(const short8*)&As[(wm + i * 16 + col) * 72 + c * 32 + quad * 8];
        bf[i] = *(const short8*)&Bs[(wn + i * 16 + col) * 72 + c * 32 + quad * 8];
      }
#pragma unroll
      for (int i = 0; i < 2; i++)
#pragma unroll
        for (int j = 0; j < 2; j++)
          acc[i][j] = __builtin_amdgcn_mfma_f32_16x16x32_bf16(af[i], bf[j], acc[i][j], 0, 0, 0);
    }
    if (it < 11) {
      unsigned short* An = SM[(it + 1) & 1][0];
      unsigned short* Bn = SM[(it + 1) & 1][1];
      *(u32x4*)&An[srow * 72 + sch] = ra[0];
      *(u32x4*)&An[(srow + 32) * 72 + sch] = ra[1];
      *(u32x4*)&Bn[srow * 72 + sch] = rb[0];
      *(u32x4*)&Bn[(srow + 32) * 72 + sch] = rb[1];
      if (it < 10) {
        int hh = it + 2;
        ra[0] = *(const u32x4*)&zpre[((size_t)(bA0 * 12 + hh) * 1024 + lA0) * 64 + sch];
        ra[1] = *(const u32x4*)&zpre[((size_t)(bA1 * 12 + hh) * 1024 + lA1) * 64 + sch];
        rb[0] = *(const u32x4*)&wot[(size_t)(n0 + srow) * 768 + hh * 64 + sch];
        rb[1] = *(const u32x4*)&wot[(size_t)(n0 + srow + 32) * 768 + hh * 64 + sch];
      }
      __syncthreads();
    }
  }
#pragma unroll
  for (int j = 0; j < 2; j++) {
    int gn = n0 + wn + j * 16 + col;
    float bsv = wob[gn];
#pragma unroll
    for (int i = 0; i < 2; i++) {
#pragma unroll
      for (int r = 0; r < 4; r++) {
        int gm = m0 + wm + i * 16 + quad * 4 + r;
        zout[(size_t)gm * 768 + gn] = acc[i][j][r] + bsv;
      }
    }
  }
}

// ---------------------------------------------------------------------------
extern "C" void kernel_launch(void* const* d_in, const int* in_sizes, int n_in,
                              void* d_out, int out_size, void* d_ws, size_t ws_size,
                              hipStream_t stream) {
  const float* qx   = (const float*)d_in[0];
  const float* kx   = (const float*)d_in[1];
  const float* vx   = (const float*)d_in[2];
  const float* WQ_w = (const float*)d_in[3];
  const float* WQ_b = (const float*)d_in[4];
  const float* WK_w = (const float*)d_in[5];
  const float* WK_b = (const float*)d_in[6];
  const float* WV_w = (const float*)d_in[7];
  const float* WV_b = (const float*)d_in[8];
  const float* WO_w = (const float*)d_in[9];
  const float* WO_b = (const float*)d_in[10];
  const float* embK = (const float*)d_in[11];
  const float* embB = (const float*)d_in[12];
  const float* preS = (const float*)d_in[13];
  const int* maskP  = (const int*)d_in[14];

  float* zout = (float*)d_out;                       // [4,1024,768]
  float* scores = zout + 3145728;                    // [4,12,1024,1024]
  unsigned short* xbf = (unsigned short*)scores;     // scratch overlay (dead before attn)

  char* ws = (char*)d_ws;
  unsigned short* wt  = (unsigned short*)(ws);               // 4x768x768 bf16
  unsigned short* qb  = (unsigned short*)(ws + 4718592);     // [B,H,L,64] bf16
  unsigned short* kb  = (unsigned short*)(ws + 11010048);    // [B,H,L,64]
  unsigned short* vtb = (unsigned short*)(ws + 17301504);    // [B,H,64,L]
  unsigned short* zp  = (unsigned short*)(ws + 23592960);    // [B,H,L,64]

  conv_x_kernel<<<9216, 256, 0, stream>>>(qx, kx, vx, xbf);
  conv_w_kernel<<<576, 256, 0, stream>>>(WQ_w, WK_w, WV_w, WO_w, wt);
  qkv_gemm_kernel<<<576, 256, 0, stream>>>(xbf, wt, WQ_b, WK_b, WV_b, qb, kb, vtb);
  attn_kernel<<<768, 256, 0, stream>>>(qb, kb, vtb, preS, maskP, embK, embB, scores, zp);
  out_gemm_kernel<<<192 * 4, 256, 0, stream>>>(zp, wt + 3 * 589824, WO_b, zout);
}